// Round 12
// baseline (178.897 us; speedup 1.0000x reference)
//
#include <hip/hip_runtime.h>
#include <stdint.h>

typedef _Float16 f16;
typedef _Float16 f16x2 __attribute__((ext_vector_type(2)));
typedef _Float16 f16x8 __attribute__((ext_vector_type(8)));
typedef float f32x4 __attribute__((ext_vector_type(4)));
typedef float f32x16 __attribute__((ext_vector_type(16)));
typedef uint32_t u32x4 __attribute__((ext_vector_type(4)));

#define B_   4
#define S_   2048
#define E_   1024
#define H_   16
#define HD_  64
#define BH_  (B_ * H_)

template <int N> struct IC { static constexpr int v = N; };

// ---------------------------------------------------------------- helpers
__device__ __forceinline__ void async_lds16(const void* g, void* l) {
    __builtin_amdgcn_global_load_lds(
        (__attribute__((address_space(1))) void*)(uintptr_t)g,
        (__attribute__((address_space(3))) void*)(uint32_t)(uintptr_t)l,
        16, 0, 0);
}

// ---------------------------------------------------------------- fp32 -> fp16
__global__ __launch_bounds__(256)
void cvt_f32_to_f16(const float* __restrict__ in, f16* __restrict__ out, int n8) {
    int i = blockIdx.x * 256 + threadIdx.x;
    if (i >= n8) return;
    const float4* p = (const float4*)in;
    float4 a = p[2 * i], b = p[2 * i + 1];
    f16x8 o;
    o[0] = (f16)a.x; o[1] = (f16)a.y; o[2] = (f16)a.z; o[3] = (f16)a.w;
    o[4] = (f16)b.x; o[5] = (f16)b.y; o[6] = (f16)b.z; o[7] = (f16)b.w;
    *(f16x8*)(out + 8 * (long)i) = o;
}

// ---------------------------------------------------------------- GEMM  C = A[M,K] * B[N,K]^T
// v3: 128xTN tile (TN=256 for QKV, 128 for out-proj), 4 waves, wave tile
// 64x(TN/2) of 32x32x16 MFMA frags. vs v2: 4096 FLOP/cyc MFMA (was 3413) and
// 0.75 ds_read per 32kFLOP (was 1.0). Same ping-pong sync skeleton, same
// staging XOR-swizzle, same epilogues reindexed for the 32x32 C layout
// (row=(reg&3)+8*(reg>>2)+4*h2, col=q32).
template <int MODE, int TN>
__global__ __launch_bounds__(256)
void gemm_bt(const f16* __restrict__ A, const f16* __restrict__ Bm,
             const float* __restrict__ bias, float* __restrict__ Cf,
             f16* __restrict__ qo, f16* __restrict__ ko, f16* __restrict__ vto,
             int M, int N, int K)
{
    constexpr int NF = TN >> 6;                 // N-frags per wave (4 or 2)
    __shared__ __align__(16) f16 As[2][128 * 32];
    __shared__ __align__(16) f16 Bs[2][TN * 32];
    const int tid = threadIdx.x, wave = tid >> 6, lane = tid & 63;
    const int q32 = lane & 31, h2 = lane >> 5;
    const int wm = wave >> 1, wn = wave & 1;
    const int ntn = N / TN;
    const int tm = blockIdx.x / ntn, tn = blockIdx.x % ntn;
    const long bm0 = (long)tm * 128, bn0 = (long)tn * TN;

#define GSTAGE(BUF, K0)  do {                                                     \
    _Pragma("unroll")                                                             \
    for (int p = 0; p < 2; ++p) {                                                 \
        const int c = p * 256 + tid;                                              \
        const int row = c >> 2;                                                   \
        const int sxc = ((c & 3) ^ ((c >> 3) & 3)) * 8;                           \
        async_lds16(A + (bm0 + row) * K + (K0) + sxc,                             \
                    &As[BUF][(p * 256 + wave * 64) * 8]);                         \
    }                                                                             \
    _Pragma("unroll")                                                             \
    for (int p = 0; p < NF; ++p) {                                                \
        const int c = p * 256 + tid;                                              \
        const int row = c >> 2;                                                   \
        const int sxc = ((c & 3) ^ ((c >> 3) & 3)) * 8;                           \
        async_lds16(Bm + (bn0 + row) * K + (K0) + sxc,                            \
                    &Bs[BUF][(p * 256 + wave * 64) * 8]);                         \
    } } while (0)

    f32x16 acc[2][NF] = {};

    auto compute = [&](auto bufc) {
        constexpr int BUF = decltype(bufc)::v;
        f16x8 af[2][2], bf[NF][2];
#pragma unroll
        for (int mi = 0; mi < 2; ++mi) {
            const int row = wm * 64 + mi * 32 + q32;
#pragma unroll
            for (int kh = 0; kh < 2; ++kh)
                af[mi][kh] = *(const f16x8*)&As[BUF][row * 32 + (((kh * 2 + h2) ^ ((row >> 1) & 3)) * 8)];
        }
#pragma unroll
        for (int ni = 0; ni < NF; ++ni) {
            const int row = wn * (TN / 2) + ni * 32 + q32;
#pragma unroll
            for (int kh = 0; kh < 2; ++kh)
                bf[ni][kh] = *(const f16x8*)&Bs[BUF][row * 32 + (((kh * 2 + h2) ^ ((row >> 1) & 3)) * 8)];
        }
        __builtin_amdgcn_s_setprio(1);
#pragma unroll
        for (int mi = 0; mi < 2; ++mi)
#pragma unroll
            for (int ni = 0; ni < NF; ++ni)
#pragma unroll
                for (int kh = 0; kh < 2; ++kh)
                    acc[mi][ni] = __builtin_amdgcn_mfma_f32_32x32x16_f16(
                        af[mi][kh], bf[ni][kh], acc[mi][ni], 0, 0, 0);
        __builtin_amdgcn_s_setprio(0);
    };

    GSTAGE(0, 0);
    __syncthreads();
    for (int k0 = 0; k0 < K; k0 += 64) {
        GSTAGE(1, k0 + 32);
        compute(IC<0>{});
        __syncthreads();
        if (k0 + 64 < K) GSTAGE(0, k0 + 64);
        compute(IC<1>{});
        __syncthreads();
    }
#undef GSTAGE

    if (MODE == 1) {
#pragma unroll
        for (int mi = 0; mi < 2; ++mi)
#pragma unroll
            for (int ni = 0; ni < NF; ++ni)
#pragma unroll
                for (int reg = 0; reg < 16; ++reg) {
                    const long r = bm0 + wm * 64 + mi * 32 + (reg & 3) + 8 * (reg >> 2) + 4 * h2;
                    const int cn = (int)bn0 + wn * (TN / 2) + ni * 32 + q32;
                    Cf[r * N + cn] = acc[mi][ni][reg] + bias[cn];
                }
        return;
    }

    // MODE 0: whole TN=256 tile lies in one of q/k/v (256 | 1024)
    const int which = (int)(bn0 >> 10);
    if (which < 2) {
#pragma unroll
        for (int mi = 0; mi < 2; ++mi)
#pragma unroll
            for (int ni = 0; ni < NF; ++ni)
#pragma unroll
                for (int reg = 0; reg < 16; ++reg) {
                    const long r = bm0 + wm * 64 + mi * 32 + (reg & 3) + 8 * (reg >> 2) + 4 * h2;
                    const int cn = (int)bn0 + wn * (TN / 2) + ni * 32 + q32;
                    const int e = cn & 1023, h = e >> 6, d = e & 63;
                    const int b = (int)(r >> 11), s = (int)(r & 2047);
                    const long bh = (long)b * H_ + h;
                    const f16 hv = (f16)(acc[mi][ni][reg] + bias[cn]);
                    if (which == 0) qo[(bh * S_ + s) * HD_ + d] = hv;
                    else            ko[(bh * S_ + s) * HD_ + d] = hv;
                }
    } else {
        // v: per-wave 64x64 LDS transposes (two col-halves), coalesced vT rows.
        // Loop ended with __syncthreads(); Bs free; wave-private T regions.
        f16* T = ((f16*)Bs) + wave * 4096;
#pragma unroll
        for (int half = 0; half < 2; ++half) {
#pragma unroll
            for (int nn = 0; nn < 2; ++nn) {
                const int ni = half * 2 + nn;
                const int dl = nn * 32 + q32;
                const int dx = dl & 7;
                const int cn = (int)bn0 + wn * 128 + ni * 32 + q32;
#pragma unroll
                for (int mi = 0; mi < 2; ++mi)
#pragma unroll
                    for (int reg = 0; reg < 16; ++reg) {
                        const int sl = mi * 32 + (reg & 3) + 8 * (reg >> 2) + 4 * h2;
                        T[dl * 64 + ((((sl >> 3) ^ dx) << 3) | (sl & 7))] =
                            (f16)(acc[mi][ni][reg] + bias[cn]);
                    }
            }
            const int b = (int)(bm0 >> 11);
            const int sbase = (int)(bm0 & 2047) + wm * 64;
            const int col0 = (int)(bn0 & 1023) + wn * 128 + half * 64;
            const int h = col0 >> 6;
            const long vbase = (long)(b * H_ + h) * HD_;
#pragma unroll
            for (int it = 0; it < 8; ++it) {
                const int d = it * 8 + (lane >> 3);
                const int schunk = lane & 7;
                u32x4 val = *(const u32x4*)&T[d * 64 + ((schunk ^ (d & 7)) << 3)];
                *(u32x4*)&vto[(vbase + d) * S_ + sbase + schunk * 8] = val;
            }
        }
    }
}

// ---------------------------------------------------------------- causal flash attention
// v9 (unchanged): 32x32 swapped QK, in-register P, chunk-major LDS, static
// ping-pong, strip pairing, raw v_exp_f32 softmax, dot2 row-sums.
__global__ __launch_bounds__(256)
void attn_fwd(const f16* __restrict__ qb, const f16* __restrict__ kb,
              const f16* __restrict__ vtb, f16* __restrict__ ob)
{
    __shared__ __align__(16) f16 Ks[2][64 * 64];   // chunk-major: [c=d/8][kv]
    __shared__ __align__(16) f16 Vs[2][64 * 64];   // chunk-major: [c=kv/8][d]
    const int tid = threadIdx.x, wave = tid >> 6, lane = tid & 63;
    const int q32 = lane & 31, h2 = lane >> 5;
    const int bh = blockIdx.y;
    const int qtA = blockIdx.x;          // 0..7
    const int qtB = 15 - qtA;            // 8..15
    const int qwA = qtA * 128 + wave * 32;
    const int qwB = qtB * 128 + wave * 32;
    const long krow0 = (long)bh * S_;
    const long vrow0 = (long)bh * HD_;

#define STAGE(BUF, KV)  do {                                                      \
    _Pragma("unroll")                                                             \
    for (int p = 0; p < 2; ++p) {                                                 \
        const int n = p * 256 + tid;                                              \
        const int base = (p * 256 + wave * 64) * 8;                               \
        async_lds16(kb  + (krow0 + (KV) + (n & 63)) * HD_ + (n >> 6) * 8, &Ks[BUF][base]); \
        async_lds16(vtb + (vrow0 + (n & 63)) * S_ + (KV) + (n >> 6) * 8, &Vs[BUF][base]);  \
    } } while (0)

    f16x8 qfA[4], qfB[4];
    const f16 sch = (f16)0.1803368801f;
#pragma unroll
    for (int kkq = 0; kkq < 4; ++kkq) {
        qfA[kkq] = *(const f16x8*)&qb[(krow0 + qwA + q32) * HD_ + kkq * 16 + h2 * 8];
        qfB[kkq] = *(const f16x8*)&qb[(krow0 + qwB + q32) * HD_ + kkq * 16 + h2 * 8];
#pragma unroll
        for (int e = 0; e < 8; ++e) { qfA[kkq][e] *= sch; qfB[kkq][e] *= sch; }
    }

    f32x16 oaccA[2] = {}, oaccB[2] = {};
    float lA = 0.f, lB = 0.f;
    const f16x2 ones2 = { (f16)1.0f, (f16)1.0f };

    auto computeS = [&](auto bufc, auto spc, int t) {
        constexpr int BUF = decltype(bufc)::v;
        constexpr int SP  = decltype(spc)::v;
        const int qw = SP ? qwB : qwA;
        const f16x8* qf = SP ? qfB : qfA;
        f32x16* oacc = SP ? oaccB : oaccA;
        float& l_part = SP ? lB : lA;
        const int kv0 = t * 64;
        if (kv0 > qw + 31) return;     // strip done (fully masked)
        const int qg = qw + q32;

        f32x16 sc[2] = {};
        __builtin_amdgcn_s_setprio(1);
#pragma unroll
        for (int kkq = 0; kkq < 4; ++kkq)
#pragma unroll
            for (int ni = 0; ni < 2; ++ni) {
                f16x8 kf = *(const f16x8*)&Ks[BUF][(((kkq * 2 + h2) * 64) + ni * 32 + q32) * 8];
                sc[ni] = __builtin_amdgcn_mfma_f32_32x32x16_f16(kf, qf[kkq], sc[ni], 0, 0, 0);
            }
        __builtin_amdgcn_s_setprio(0);

        const bool maskp = (kv0 + 63) > qw;
#pragma unroll
        for (int ni = 0; ni < 2; ++ni)
#pragma unroll
            for (int r = 0; r < 16; ++r) {
                float p = __builtin_amdgcn_exp2f(sc[ni][r]);
                const int kvg = kv0 + ni * 32 + (r & 3) + 8 * (r >> 2) + 4 * h2;
                if (maskp && kvg > qg) p = 0.0f;
                sc[ni][r] = p;
            }

        __builtin_amdgcn_s_setprio(1);
#pragma unroll
        for (int ni = 0; ni < 2; ++ni) {
            uint32_t u[8];
#pragma unroll
            for (int m = 0; m < 8; ++m) {
                auto hp = __builtin_amdgcn_cvt_pkrtz(sc[ni][2 * m], sc[ni][2 * m + 1]);
                u[m] = __builtin_bit_cast(uint32_t, hp);
                l_part = __builtin_amdgcn_fdot2(__builtin_bit_cast(f16x2, u[m]), ones2, l_part, false);
            }
#pragma unroll
            for (int kkv = 0; kkv < 2; ++kkv) {
                auto sA = __builtin_amdgcn_permlane32_swap(u[4 * kkv + 0], u[4 * kkv + 2], false, false);
                auto sB = __builtin_amdgcn_permlane32_swap(u[4 * kkv + 1], u[4 * kkv + 3], false, false);
                u32x4 uv = { (uint32_t)sA[0], (uint32_t)sB[0], (uint32_t)sA[1], (uint32_t)sB[1] };
                f16x8 pf = __builtin_bit_cast(f16x8, uv);
                const int kg = ni * 2 + kkv;
#pragma unroll
                for (int dh = 0; dh < 2; ++dh) {
                    f16x8 vf = *(const f16x8*)&Vs[BUF][(((kg * 2 + h2) * 64) + dh * 32 + q32) * 8];
                    oacc[dh] = __builtin_amdgcn_mfma_f32_32x32x16_f16(pf, vf, oacc[dh], 0, 0, 0);
                }
            }
        }
        __builtin_amdgcn_s_setprio(0);
    };

    const int ntB = 2 * (qtB + 1);    // 18..32, even; strip B is the long one
    STAGE(0, 0);
    __syncthreads();
    for (int t = 0; t < ntB; t += 2) {
        STAGE(1, (t + 1) * 64);
        computeS(IC<0>{}, IC<0>{}, t);
        computeS(IC<0>{}, IC<1>{}, t);
        __syncthreads();
        if (t + 2 < ntB) STAGE(0, (t + 2) * 64);
        computeS(IC<1>{}, IC<0>{}, t + 1);
        computeS(IC<1>{}, IC<1>{}, t + 1);
        __syncthreads();
    }
#undef STAGE

    const int b = bh >> 4, h = bh & 15;
    const float invA = 1.0f / (lA + __shfl_xor(lA, 32));
    const float invB = 1.0f / (lB + __shfl_xor(lB, 32));
#pragma unroll
    for (int r = 0; r < 16; ++r) {
        const int crow = (r & 3) + 8 * (r >> 2) + 4 * h2;
        const float irA = __shfl(invA, crow);
        const float irB = __shfl(invB, crow);
#pragma unroll
        for (int dh = 0; dh < 2; ++dh) {
            ob[((long)b * S_ + qwA + crow) * E_ + h * HD_ + dh * 32 + q32] = (f16)(oaccA[dh][r] * irA);
            ob[((long)b * S_ + qwB + crow) * E_ + h * HD_ + dh * 32 + q32] = (f16)(oaccB[dh][r] * irB);
        }
    }
}

// ---------------------------------------------------------------- launch
extern "C" void kernel_launch(void* const* d_in, const int* in_sizes, int n_in,
                              void* d_out, int out_size, void* d_ws, size_t ws_size,
                              hipStream_t stream)
{
    (void)in_sizes; (void)n_in; (void)out_size; (void)ws_size;
    const float* x  = (const float*)d_in[0];
    const float* w1 = (const float*)d_in[1];
    const float* b1 = (const float*)d_in[2];
    const float* w2 = (const float*)d_in[3];
    const float* b2 = (const float*)d_in[4];
    float* out = (float*)d_out;

    char* ws = (char*)d_ws;
    f16* xb  = (f16*)ws;  ws += (size_t)8192 * 1024 * 2;
    f16* w1b = (f16*)ws;  ws += (size_t)3072 * 1024 * 2;
    f16* w2b = (f16*)ws;  ws += (size_t)1024 * 1024 * 2;
    f16* qb  = (f16*)ws;  ws += (size_t)BH_ * S_ * HD_ * 2;
    f16* kb  = (f16*)ws;  ws += (size_t)BH_ * S_ * HD_ * 2;
    f16* vtb = (f16*)ws;  ws += (size_t)BH_ * S_ * HD_ * 2;
    f16* ao  = (f16*)ws;  ws += (size_t)8192 * 1024 * 2;

    cvt_f32_to_f16<<<dim3(8192 * 1024 / 8 / 256), dim3(256), 0, stream>>>(x,  xb,  8192 * 1024 / 8);
    cvt_f32_to_f16<<<dim3(3072 * 1024 / 8 / 256), dim3(256), 0, stream>>>(w1, w1b, 3072 * 1024 / 8);
    cvt_f32_to_f16<<<dim3(1024 * 1024 / 8 / 256), dim3(256), 0, stream>>>(w2, w2b, 1024 * 1024 / 8);

    gemm_bt<0, 256><<<dim3(64 * 12), dim3(256), 0, stream>>>(
        xb, w1b, b1, nullptr, qb, kb, vtb, 8192, 3072, 1024);

    attn_fwd<<<dim3(8, 64), dim3(256), 0, stream>>>(qb, kb, vtb, ao);

    gemm_bt<1, 128><<<dim3(64 * 8), dim3(256), 0, stream>>>(
        ao, w2b, b2, out, nullptr, nullptr, nullptr, 8192, 1024, 1024);
}